// Round 1
// baseline (28.131 us; speedup 1.0000x reference)
//
#include <hip/hip_runtime.h>
#include <math.h>

namespace {
constexpr int Nn = 4, Hh = 256, Ww = 256;
constexpr int HW = Hh * Ww;
constexpr int P  = Nn * HW;          // 262144 pixels
constexpr float ZFAR  = 100.0f;
constexpr float ZNEAR = 1.0f;
constexpr float INV_SIG = 1.0f / (1e-4f + 1e-8f);   // 1/(SIGMA+1e-8)
constexpr float INV_GAM = 1.0f / 1e-4f;             // 1/GAMMA
constexpr float EPSF    = 1e-10f;
constexpr float INV_ZR  = 1.0f / (ZFAR - ZNEAR);
}

#define FMA4(A, C, Rp, i)                                   \
    {                                                       \
        float4 _t = (Rp)[i];                                \
        A.x = fmaf((C), _t.x, A.x);                         \
        A.y = fmaf((C), _t.y, A.y);                         \
        A.z = fmaf((C), _t.z, A.z);                         \
        A.w = fmaf((C), _t.w, A.w);                         \
    }

__global__ __launch_bounds__(256) void render_kernel(
    const float* __restrict__ vf,     // (V,16)
    const float* __restrict__ bary,   // (P,8,3)
    const float* __restrict__ dists,  // (P,8)
    const float* __restrict__ zbuf,   // (P,8)
    const int*  __restrict__ faces,   // (F,3)
    const int*  __restrict__ p2f,     // (P,8)
    float* __restrict__ out)          // (N,17,H,W)
{
    const int p = blockIdx.x * blockDim.x + threadIdx.x;
    if (p >= P) return;

    // ---- vectorized per-pixel loads ----
    const int4* fp = reinterpret_cast<const int4*>(p2f + (size_t)p * 8);
    int4 fa = fp[0], fb = fp[1];
    int fk[8] = {fa.x, fa.y, fa.z, fa.w, fb.x, fb.y, fb.z, fb.w};

    const float4* dp = reinterpret_cast<const float4*>(dists + (size_t)p * 8);
    float4 da = dp[0], db = dp[1];
    float dk[8] = {da.x, da.y, da.z, da.w, db.x, db.y, db.z, db.w};

    const float4* zp = reinterpret_cast<const float4*>(zbuf + (size_t)p * 8);
    float4 za = zp[0], zb = zp[1];
    float zk[8] = {za.x, za.y, za.z, za.w, zb.x, zb.y, zb.z, zb.w};

    const float4* bp = reinterpret_cast<const float4*>(bary + (size_t)p * 24);
    float4 b0 = bp[0], b1 = bp[1], b2 = bp[2], b3 = bp[3], b4 = bp[4], b5 = bp[5];
    float bc[24] = {b0.x, b0.y, b0.z, b0.w,
                    b1.x, b1.y, b1.z, b1.w,
                    b2.x, b2.y, b2.z, b2.w,
                    b3.x, b3.y, b3.z, b3.w,
                    b4.x, b4.y, b4.z, b4.w,
                    b5.x, b5.y, b5.z, b5.w};

    // ---- pass 1: prob (sigmoid), z_inv, alpha product, z_max ----
    float prob[8], zi[8];
    float keep = 1.0f;     // prod(1 - prob)
    float zmax = EPSF;     // clip(max(z_inv), EPS)
#pragma unroll
    for (int k = 0; k < 8; ++k) {
        const bool valid = fk[k] >= 0;
        // sigmoid(-d/sigma) = 1/(1+exp(d/sigma))
        float pr = valid ? 1.0f / (1.0f + __expf(dk[k] * INV_SIG)) : 0.0f;
        prob[k] = pr;
        keep *= (1.0f - pr);
        float zv = valid ? (ZFAR - zk[k]) * INV_ZR : 0.0f;
        zi[k] = zv;
        zmax = fmaxf(zmax, zv);
    }

    // ---- pass 2: softmax weights ----
    const float delta = fmaxf(__expf((EPSF - zmax) * INV_GAM), EPSF);
    float denom = delta;
    float wk_[8];
#pragma unroll
    for (int k = 0; k < 8; ++k) {
        float wv = prob[k] * __expf((zi[k] - zmax) * INV_GAM);
        wk_[k] = wv;
        denom += wv;
    }

    // ---- pass 3: gather + interpolate only contributing samples ----
    float4 acc0 = make_float4(0.f, 0.f, 0.f, 0.f);
    float4 acc1 = make_float4(0.f, 0.f, 0.f, 0.f);
    float4 acc2 = make_float4(0.f, 0.f, 0.f, 0.f);
    float4 acc3 = make_float4(0.f, 0.f, 0.f, 0.f);
#pragma unroll
    for (int k = 0; k < 8; ++k) {
        const float wv = wk_[k];
        if (wv != 0.0f) {              // implies fk[k] >= 0
            const int f = fk[k];
            const int v0 = faces[f * 3 + 0];
            const int v1 = faces[f * 3 + 1];
            const int v2 = faces[f * 3 + 2];
            const float c0 = wv * bc[k * 3 + 0];
            const float c1 = wv * bc[k * 3 + 1];
            const float c2 = wv * bc[k * 3 + 2];
            const float4* r0 = reinterpret_cast<const float4*>(vf + (size_t)v0 * 16);
            const float4* r1 = reinterpret_cast<const float4*>(vf + (size_t)v1 * 16);
            const float4* r2 = reinterpret_cast<const float4*>(vf + (size_t)v2 * 16);
            FMA4(acc0, c0, r0, 0); FMA4(acc1, c0, r0, 1);
            FMA4(acc2, c0, r0, 2); FMA4(acc3, c0, r0, 3);
            FMA4(acc0, c1, r1, 0); FMA4(acc1, c1, r1, 1);
            FMA4(acc2, c1, r1, 2); FMA4(acc3, c1, r1, 3);
            FMA4(acc0, c2, r2, 0); FMA4(acc1, c2, r2, 1);
            FMA4(acc2, c2, r2, 2); FMA4(acc3, c2, r2, 3);
        }
    }

    // ---- epilogue: divide by denom, store channel-major ----
    const float invden = 1.0f / denom;
    const int n  = p / HW;
    const int hw = p - n * HW;
    float* o = out + (size_t)n * 17 * HW + hw;
    o[(size_t)0  * HW] = acc0.x * invden;
    o[(size_t)1  * HW] = acc0.y * invden;
    o[(size_t)2  * HW] = acc0.z * invden;
    o[(size_t)3  * HW] = acc0.w * invden;
    o[(size_t)4  * HW] = acc1.x * invden;
    o[(size_t)5  * HW] = acc1.y * invden;
    o[(size_t)6  * HW] = acc1.z * invden;
    o[(size_t)7  * HW] = acc1.w * invden;
    o[(size_t)8  * HW] = acc2.x * invden;
    o[(size_t)9  * HW] = acc2.y * invden;
    o[(size_t)10 * HW] = acc2.z * invden;
    o[(size_t)11 * HW] = acc2.w * invden;
    o[(size_t)12 * HW] = acc3.x * invden;
    o[(size_t)13 * HW] = acc3.y * invden;
    o[(size_t)14 * HW] = acc3.z * invden;
    o[(size_t)15 * HW] = acc3.w * invden;
    o[(size_t)16 * HW] = 1.0f - keep;   // alpha
}

extern "C" void kernel_launch(void* const* d_in, const int* in_sizes, int n_in,
                              void* d_out, int out_size, void* d_ws, size_t ws_size,
                              hipStream_t stream) {
    const float* vf    = (const float*)d_in[0];
    const float* bary  = (const float*)d_in[1];
    const float* dists = (const float*)d_in[2];
    const float* zbuf  = (const float*)d_in[3];
    const int*   faces = (const int*)d_in[4];
    const int*   p2f   = (const int*)d_in[5];
    float* out = (float*)d_out;

    render_kernel<<<dim3(P / 256), dim3(256), 0, stream>>>(
        vf, bary, dists, zbuf, faces, p2f, out);
}